// Round 15
// baseline (554.654 us; speedup 1.0000x reference)
//
#include <hip/hip_runtime.h>
#include <hip/hip_bf16.h>
#include <math.h>

// Problem constants
#define BB   64
#define SS   1024
#define S1C  1025
#define DD   64
#define NHD  4
#define NBH  (BB * NHD)      // 256
#define DHD  16
#define DFFC 256
#define NLAY 3
#define NTOK (BB * S1C)      // 65600 = 64 * 1025
#define SPAD 1056            // padded key/seq length (66 * 16)
#define TGRP2 9              // tile-pair groups: wave covers T0=grp*4+w, T1=T0+36
#define FTT   16             // tokens per block (k_qkv)
#define FT2   64             // tokens per block (k_block) - 4 token-tiles/wave
#define HPAD 264             // hid row stride in shorts
#define OPAD 68              // ot row stride in floats
#define YPAD 72              // ys row stride in shorts
#define QSCL 0.36067376022224085f   // 0.25 * log2(e) folded into q

typedef const float* fp;
typedef __attribute__((ext_vector_type(8))) short bf16x8;
typedef __attribute__((ext_vector_type(4))) float f32x4;

#if __has_builtin(__builtin_amdgcn_exp2f)
#define RAW_EXP2(x) __builtin_amdgcn_exp2f(x)
#else
#define RAW_EXP2(x) __expf(0.6931471805599453f * (x))
#endif
#if __has_builtin(__builtin_amdgcn_rcpf)
#define RAW_RCP(x) __builtin_amdgcn_rcpf(x)
#else
#define RAW_RCP(x) (1.0f / (x))
#endif

__device__ __forceinline__ float gelu_exact(float x) {
    return 0.5f * x * (1.0f + erff(x * 0.7071067811865475f));
}
// A&S 7.1.26 erf approximation, |err| <= 1.5e-7 (<< bf16 rounding noise)
__device__ __forceinline__ float erf_fast(float x) {
    float ax = fabsf(x);
    float t = RAW_RCP(1.0f + 0.3275911f * ax);
    float p = t * (0.254829592f + t * (-0.284496736f + t * (1.421413741f +
              t * (-1.453152027f + t * 1.061405429f))));
    float e = RAW_EXP2(ax * ax * -1.4426950408889634f);
    float r = 1.0f - p * e;
    return copysignf(r, x);
}
__device__ __forceinline__ float gelu_fast(float x) {
    return 0.5f * x * (1.0f + erf_fast(x * 0.7071067811865475f));
}
// RTNE float->bf16 (finite values), 3 ops
__device__ __forceinline__ short f2b(float f) {
    unsigned u = __float_as_uint(f);
    return (short)((u + 0x7fffu + ((u >> 16) & 1u)) >> 16);
}
// fast bf16 for positive finite values (round-nearest-up)
__device__ __forceinline__ short f2b_pos(float f) {
    return (short)((__float_as_uint(f) + 0x8000u) >> 16);
}

// ---------------------------------------------------------------------------
// Kernel W: one-shot weight convert+transpose to bf16 [n][k] fragments.
// ---------------------------------------------------------------------------
__global__ __launch_bounds__(256) void k_wconv(
    fp wq, fp wk, fp wv, fp wo, fp w1, fp w2,
    short* __restrict__ wqkvT, short* __restrict__ woT,
    short* __restrict__ w1T, short* __restrict__ w2T)
{
    int l = blockIdx.y;
    int i = blockIdx.x * 256 + threadIdx.x;
    if (i < 12288) {
        int p = i >> 12, rem = i & 4095;
        int d = rem >> 6, j = rem & 63;
        fp src = (p == 0 ? wq : p == 1 ? wk : wv) + (size_t)l * 4096;
        float v = src[j * 64 + d];
        if (p == 0) v *= QSCL;
        wqkvT[(size_t)l * 12288 + i] = f2b(v);
    } else if (i < 16384) {
        int rem = i - 12288;
        woT[(size_t)l * 4096 + rem] = f2b(wo[(size_t)l * 4096 + (rem & 63) * 64 + (rem >> 6)]);
    } else if (i < 32768) {
        int rem = i - 16384;
        w1T[(size_t)l * 16384 + rem] = f2b(w1[(size_t)l * 16384 + (rem & 63) * 256 + (rem >> 6)]);
    } else {
        int rem = i - 32768;
        w2T[(size_t)l * 16384 + rem] = f2b(w2[(size_t)l * 16384 + (rem & 255) * 64 + (rem >> 8)]);
    }
}

// ---------------------------------------------------------------------------
// Kernel 0: zero the pad regions of the bf16 q/k/v buffers (rows 1025..1055).
// ---------------------------------------------------------------------------
__global__ __launch_bounds__(64) void k_zero(
    short* __restrict__ qb, short* __restrict__ kb, short* __restrict__ vbt)
{
    int bh = blockIdx.x, t = threadIdx.x;
    for (int i = t; i < 31 * 16; i += 64) {
        int r = i >> 4, c = i & 15;
        size_t idx = ((size_t)bh * SPAD + 1025 + r) * 16 + c;
        qb[idx] = 0; kb[idx] = 0;
    }
    for (int i = t; i < 16 * 31; i += 64) {
        int e = i / 31, c = i % 31;
        vbt[((size_t)bh * 16 + e) * SPAD + 1025 + c] = 0;
    }
}

// ---------------------------------------------------------------------------
// Kernel 1: encoder MLP + sos concat + positional encoding -> x fp32, xb bf16
// ---------------------------------------------------------------------------
__global__ __launch_bounds__(256) void k_encode(
    fp in_seq, fp enc_w1, fp enc_b1, fp enc_w2, fp enc_b2, fp sos,
    float* __restrict__ x, short* __restrict__ xb)
{
    int t = threadIdx.x;
    int w = t >> 6, d = t & 63;
    int tok = blockIdx.x * 4 + w;
    int b = tok / S1C, s = tok % S1C;
    __shared__ float e[4][48];
    float val;
    if (s == 0) {
        val = sos[d];
    } else {
        float tin = in_seq[b * SS + (s - 1)];
        if (d < 48) e[w][d] = gelu_fast(tin * enc_w1[d] + enc_b1[d]);
        float acc = enc_b2[d];
        for (int j = 0; j < 48; ++j) acc += e[w][j] * enc_w2[j * DD + d];
        val = acc;
    }
    int i2 = (d >> 1) * 2;
    float factor = RAW_EXP2((float)i2 * (-9.210340371976184f / 64.0f) * 1.4426950408889634f);
    float ang = (float)s * factor;
    val += (d & 1) ? __cosf(ang) : __sinf(ang);
    x[(size_t)tok * DD + d] = val;
    xb[(size_t)tok * DD + d] = f2b(val);
}

// ---------------------------------------------------------------------------
// Kernel 2: MFMA Q/K/V projection for layer 0 (reads xb from encode).
// ---------------------------------------------------------------------------
__global__ __launch_bounds__(256) void k_qkv(
    const short* __restrict__ xb, const short* __restrict__ wqkvT,
    fp bq, fp bk, fp bv,
    short* __restrict__ qb, short* __restrict__ kb, short* __restrict__ vbt)
{
    int blk = blockIdx.x, t = threadIdx.x;
    int tok0 = blk * FTT;
    int w = t >> 6, l = t & 63;
    int quad = l >> 4, lo = l & 15;

    bf16x8 a0 = *(const bf16x8*)(xb + ((size_t)(tok0 + lo)) * DD + quad * 8);
    bf16x8 a1 = *(const bf16x8*)(xb + ((size_t)(tok0 + lo)) * DD + 32 + quad * 8);

    int tokr[4], br[4], sr[4];
    #pragma unroll
    for (int r = 0; r < 4; ++r) {
        tokr[r] = tok0 + quad * 4 + r;
        br[r] = tokr[r] / S1C; sr[r] = tokr[r] % S1C;
    }

    int n = w * 16 + lo;
    #pragma unroll
    for (int p = 0; p < 3; ++p) {
        const short* wT = wqkvT + (size_t)p * 4096 + (size_t)n * 64;
        bf16x8 b0 = *(const bf16x8*)(wT + quad * 8);
        bf16x8 b1 = *(const bf16x8*)(wT + 32 + quad * 8);
        f32x4 c = __builtin_amdgcn_mfma_f32_16x16x32_bf16(a0, b0, (f32x4){0,0,0,0}, 0, 0, 0);
        c = __builtin_amdgcn_mfma_f32_16x16x32_bf16(a1, b1, c, 0, 0, 0);
        float bias = (p == 0) ? bq[n] * QSCL : (p == 1) ? bk[n] : bv[n];
        #pragma unroll
        for (int r = 0; r < 4; ++r) {
            int bh = br[r] * NHD + w;
            short val = f2b(c[r] + bias);
            if (p == 0)      qb[((size_t)bh * SPAD + sr[r]) * 16 + lo] = val;
            else if (p == 1) kb[((size_t)bh * SPAD + sr[r]) * 16 + lo] = val;
            else             vbt[((size_t)bh * 16 + lo) * SPAD + sr[r]] = val;
        }
    }
}

// ---------------------------------------------------------------------------
// Kernel 3: single-pass flash MFMA attention, two q-tiles per wave
// (r13 best-measured version, reverted verbatim).
// ---------------------------------------------------------------------------
__global__ __launch_bounds__(256) void k_attn(
    const short* __restrict__ qb, const short* __restrict__ kb,
    const short* __restrict__ vbt, short* __restrict__ ob)
{
    int bid = blockIdx.x;
    int bh  = bid % NBH;           // 9 blocks of a bh share bid%8 (XCD/L2)
    int grp = bid / NBH;           // 0..8
    int b = bh >> 2, h = bh & 3;
    int t = threadIdx.x;
    int w = t >> 6, l = t & 63;
    int quad = l >> 4, lo = l & 15;
    int t0 = grp * 4 + w;          // 0..35
    int t1 = t0 + 36;              // 36..71
    if (t1 > 65) t1 = 65;          // clamp into zero-pad
    int qg0 = t0 * 16, qg1 = t1 * 16;

    __shared__ short pt_all[4][2][16][40];
    short (*pt0)[40] = pt_all[w][0];
    short (*pt1)[40] = pt_all[w][1];

    const short* qbase = qb + (size_t)bh * SPAD * 16;
    const short* kbase = kb + (size_t)bh * SPAD * 16;
    const short* vbase = vbt + (size_t)bh * 16 * SPAD;

    bf16x8 aQ0 = {0,0,0,0,0,0,0,0}, aQ1 = {0,0,0,0,0,0,0,0};
    if (quad < 2) {
        aQ0 = *(const bf16x8*)(qbase + ((size_t)(qg0 + lo)) * 16 + quad * 8);
        aQ1 = *(const bf16x8*)(qbase + ((size_t)(qg1 + lo)) * 16 + quad * 8);
    }

    const short ONE = 0x3F80;
    bf16x8 aOne = {ONE, ONE, ONE, ONE, ONE, ONE, ONE, ONE};

    f32x4 oc0 = {0.f,0.f,0.f,0.f}, oc1 = {0.f,0.f,0.f,0.f};
    f32x4 dn0 = {0.f,0.f,0.f,0.f}, dn1 = {0.f,0.f,0.f,0.f};

    for (int ch = 0; ch < 32; ++ch) {
        #pragma unroll
        for (int t01 = 0; t01 < 2; ++t01) {
            int krow = ch * 32 + t01 * 16 + lo;
            bf16x8 bK = *(const bf16x8*)(kbase + (size_t)krow * 16 + (quad & 1) * 8);
            f32x4 c0 = __builtin_amdgcn_mfma_f32_16x16x32_bf16(
                aQ0, bK, (f32x4){0.f,0.f,0.f,0.f}, 0, 0, 0);
            f32x4 c1 = __builtin_amdgcn_mfma_f32_16x16x32_bf16(
                aQ1, bK, (f32x4){0.f,0.f,0.f,0.f}, 0, 0, 0);
            #pragma unroll
            for (int r = 0; r < 4; ++r) {
                pt0[quad * 4 + r][t01 * 16 + lo] = f2b_pos(RAW_EXP2(c0[r]));
                pt1[quad * 4 + r][t01 * 16 + lo] = f2b_pos(RAW_EXP2(c1[r]));
            }
        }
        bf16x8 aV = *(const bf16x8*)(vbase + (size_t)lo * SPAD + ch * 32 + quad * 8);
        bf16x8 pB0 = *(const bf16x8*)&pt0[lo][quad * 8];
        oc0 = __builtin_amdgcn_mfma_f32_16x16x32_bf16(aV, pB0, oc0, 0, 0, 0);
        dn0 = __builtin_amdgcn_mfma_f32_16x16x32_bf16(aOne, pB0, dn0, 0, 0, 0);
        bf16x8 pB1 = *(const bf16x8*)&pt1[lo][quad * 8];
        oc1 = __builtin_amdgcn_mfma_f32_16x16x32_bf16(aV, pB1, oc1, 0, 0, 0);
        dn1 = __builtin_amdgcn_mfma_f32_16x16x32_bf16(aOne, pB1, dn1, 0, 0, 0);
    }
    {   // tail chunk: keys 1024..1055, only key 1024 valid
        #pragma unroll
        for (int t01 = 0; t01 < 2; ++t01) {
            int krow = 1024 + t01 * 16 + lo;
            bf16x8 bK = *(const bf16x8*)(kbase + (size_t)krow * 16 + (quad & 1) * 8);
            f32x4 c0 = __builtin_amdgcn_mfma_f32_16x16x32_bf16(
                aQ0, bK, (f32x4){0.f,0.f,0.f,0.f}, 0, 0, 0);
            f32x4 c1 = __builtin_amdgcn_mfma_f32_16x16x32_bf16(
                aQ1, bK, (f32x4){0.f,0.f,0.f,0.f}, 0, 0, 0);
            bool valid = (krow <= 1024);
            #pragma unroll
            for (int r = 0; r < 4; ++r) {
                pt0[quad * 4 + r][t01 * 16 + lo] = f2b_pos(valid ? RAW_EXP2(c0[r]) : 0.f);
                pt1[quad * 4 + r][t01 * 16 + lo] = f2b_pos(valid ? RAW_EXP2(c1[r]) : 0.f);
            }
        }
        bf16x8 aV = *(const bf16x8*)(vbase + (size_t)lo * SPAD + 1024 + quad * 8);
        bf16x8 pB0 = *(const bf16x8*)&pt0[lo][quad * 8];
        oc0 = __builtin_amdgcn_mfma_f32_16x16x32_bf16(aV, pB0, oc0, 0, 0, 0);
        dn0 = __builtin_amdgcn_mfma_f32_16x16x32_bf16(aOne, pB0, dn0, 0, 0, 0);
        bf16x8 pB1 = *(const bf16x8*)&pt1[lo][quad * 8];
        oc1 = __builtin_amdgcn_mfma_f32_16x16x32_bf16(aV, pB1, oc1, 0, 0, 0);
        dn1 = __builtin_amdgcn_mfma_f32_16x16x32_bf16(aOne, pB1, dn1, 0, 0, 0);
    }

    {
        int qrow = qg0 + lo;
        if (qrow < S1C) {
            float inv = 1.0f / dn0[0];
            unsigned p0 = (unsigned short)f2b(oc0[0] * inv) | ((unsigned)(unsigned short)f2b(oc0[1] * inv) << 16);
            unsigned p1 = (unsigned short)f2b(oc0[2] * inv) | ((unsigned)(unsigned short)f2b(oc0[3] * inv) << 16);
            *(uint2*)(ob + ((size_t)b * S1C + qrow) * DD + h * DHD + quad * 4) = make_uint2(p0, p1);
        }
    }
    {
        int qrow = qg1 + lo;
        if (qrow < S1C) {
            float inv = 1.0f / dn1[0];
            unsigned p0 = (unsigned short)f2b(oc1[0] * inv) | ((unsigned)(unsigned short)f2b(oc1[1] * inv) << 16);
            unsigned p1 = (unsigned short)f2b(oc1[2] * inv) | ((unsigned)(unsigned short)f2b(oc1[3] * inv) << 16);
            *(uint2*)(ob + ((size_t)b * S1C + qrow) * DD + h * DHD + quad * 4) = make_uint2(p0, p1);
        }
    }
}

// ---------------------------------------------------------------------------
// Kernel 4: fused transformer tail: oproj(MFMA) + LN1 + FFN(MFMA) + LN2
// + next-layer QKV(MFMA). 64 tokens/block (4 token-tiles per wave): each
// weight fragment feeds 4 MFMAs; block count halves again vs FT2=32.
// LDS 60.4 KB -> 2 blocks/CU.
// ---------------------------------------------------------------------------
__global__ __launch_bounds__(256) void k_block(
    const short* __restrict__ ob, float* __restrict__ x,
    const short* __restrict__ woT, fp bo, fp ln1s, fp ln1b,
    const short* __restrict__ w1T, fp b1, const short* __restrict__ w2T, fp b2,
    fp ln2s, fp ln2b,
    const short* __restrict__ wqkvTn, fp bqn, fp bkn, fp bvn,
    short* __restrict__ qb, short* __restrict__ kb, short* __restrict__ vbt,
    int has_next)
{
    int blk = blockIdx.x, t = threadIdx.x;
    int tok0 = blk * FT2;
    int w = t >> 6, l = t & 63;
    int quad = l >> 4, lo = l & 15;

    __shared__ float otf[FT2][OPAD];   // 17.4 KB
    __shared__ short ys[FT2][YPAD];    // 9.2 KB
    __shared__ short hid[FT2][HPAD];   // 33.8 KB

    // ---- oproj: wave w -> n = w*16+lo, all 4 token-tiles ----
    {
        int n = w * 16 + lo;
        const short* wT = woT + (size_t)n * 64;
        bf16x8 b0 = *(const bf16x8*)(wT + quad * 8);
        bf16x8 bb = *(const bf16x8*)(wT + 32 + quad * 8);
        float bov = bo[n];
        #pragma unroll
        for (int tt = 0; tt < 4; ++tt) {
            const short* obp = ob + ((size_t)(tok0 + tt * 16 + lo)) * DD;
            bf16x8 a0 = *(const bf16x8*)(obp + quad * 8);
            bf16x8 a1 = *(const bf16x8*)(obp + 32 + quad * 8);
            f32x4 c = __builtin_amdgcn_mfma_f32_16x16x32_bf16(a0, b0, (f32x4){0,0,0,0}, 0, 0, 0);
            c = __builtin_amdgcn_mfma_f32_16x16x32_bf16(a1, bb, c, 0, 0, 0);
            #pragma unroll
            for (int r = 0; r < 4; ++r)
                otf[tt * 16 + quad * 4 + r][n] = c[r] + bov;
        }
    }
    __syncthreads();

    // ---- LN1: wave w -> tokens w*16 .. w*16+15, lane = dim d ----
    int d = l;
    float yv[16];
    {
        float s1 = ln1s[d], bl1 = ln1b[d];
        #pragma unroll
        for (int i = 0; i < 16; ++i) {
            int tt = w * 16 + i;
            float val = otf[tt][d] + x[(size_t)(tok0 + tt) * DD + d];
            float sum = val, vs = val * val;
            #pragma unroll
            for (int off = 32; off > 0; off >>= 1) {
                sum += __shfl_xor(sum, off, 64);
                vs  += __shfl_xor(vs, off, 64);
            }
            float mean = sum * (1.0f / 64.0f);
            float var = vs * (1.0f / 64.0f) - mean * mean;
            float y = (val - mean) * rsqrtf(var + 1e-5f) * s1 + bl1;
            yv[i] = y;
            ys[tt][d] = f2b(y);
        }
    }
    __syncthreads();

    // ---- FFN phase 1: wave w -> n in [w*64, w*64+64), all 4 tiles ----
    {
        bf16x8 a[4][2];
        #pragma unroll
        for (int tt = 0; tt < 4; ++tt) {
            a[tt][0] = *(const bf16x8*)&ys[tt * 16 + lo][quad * 8];
            a[tt][1] = *(const bf16x8*)&ys[tt * 16 + lo][32 + quad * 8];
        }
        #pragma unroll
        for (int i = 0; i < 4; ++i) {
            int n = w * 64 + i * 16 + lo;
            const short* wT = w1T + (size_t)n * 64;
            bf16x8 b0 = *(const bf16x8*)(wT + quad * 8);
            bf16x8 bb = *(const bf16x8*)(wT + 32 + quad * 8);
            float b1v = b1[n];
            #pragma unroll
            for (int tt = 0; tt < 4; ++tt) {
                f32x4 c = __builtin_amdgcn_mfma_f32_16x16x32_bf16(a[tt][0], b0, (f32x4){0,0,0,0}, 0, 0, 0);
                c = __builtin_amdgcn_mfma_f32_16x16x32_bf16(a[tt][1], bb, c, 0, 0, 0);
                #pragma unroll
                for (int r = 0; r < 4; ++r)
                    hid[tt * 16 + quad * 4 + r][n] = f2b(gelu_fast(c[r] + b1v));
            }
        }
    }
    __syncthreads();

    // ---- FFN phase 2: wave w -> n-tile w (K=256), all 4 tiles ----
    {
        f32x4 c2[4] = {{0.f,0.f,0.f,0.f},{0.f,0.f,0.f,0.f},{0.f,0.f,0.f,0.f},{0.f,0.f,0.f,0.f}};
        const short* wT2 = w2T + (size_t)(w * 16 + lo) * 256;
        #pragma unroll
        for (int kc = 0; kc < 8; ++kc) {
            bf16x8 b2f = *(const bf16x8*)(wT2 + kc * 32 + quad * 8);
            #pragma unroll
            for (int tt = 0; tt < 4; ++tt) {
                bf16x8 a2 = *(const bf16x8*)&hid[tt * 16 + lo][kc * 32 + quad * 8];
                c2[tt] = __builtin_amdgcn_mfma_f32_16x16x32_bf16(a2, b2f, c2[tt], 0, 0, 0);
            }
        }
        float b2v = b2[w * 16 + lo];
        #pragma unroll
        for (int tt = 0; tt < 4; ++tt)
            #pragma unroll
            for (int r = 0; r < 4; ++r)
                otf[tt * 16 + quad * 4 + r][w * 16 + lo] = c2[tt][r] + b2v;
    }
    __syncthreads();

    // ---- LN2: same 16 tokens, residual = yv (registers) ----
    {
        float s2 = ln2s[d], bl2 = ln2b[d];
        #pragma unroll
        for (int i = 0; i < 16; ++i) {
            int tt = w * 16 + i;
            float val = otf[tt][d] + yv[i];
            float sum = val, vs = val * val;
            #pragma unroll
            for (int off = 32; off > 0; off >>= 1) {
                sum += __shfl_xor(sum, off, 64);
                vs  += __shfl_xor(vs, off, 64);
            }
            float mean = sum * (1.0f / 64.0f);
            float var = vs * (1.0f / 64.0f) - mean * mean;
            float y = (val - mean) * rsqrtf(var + 1e-5f) * s2 + bl2;
            x[(size_t)(tok0 + tt) * DD + d] = y;
            ys[tt][d] = f2b(y);
        }
    }
    __syncthreads();

    // ---- next-layer QKV: wave w = head w, all 4 tiles ----
    if (has_next) {
        bf16x8 a[4][2];
        #pragma unroll
        for (int tt = 0; tt < 4; ++tt) {
            a[tt][0] = *(const bf16x8*)&ys[tt * 16 + lo][quad * 8];
            a[tt][1] = *(const bf16x8*)&ys[tt * 16 + lo][32 + quad * 8];
        }
        int n = w * 16 + lo;
        #pragma unroll
        for (int p = 0; p < 3; ++p) {
            const short* wT = wqkvTn + (size_t)p * 4096 + (size_t)n * 64;
            bf16x8 b0 = *(const bf16x8*)(wT + quad * 8);
            bf16x8 bb = *(const bf16x8*)(wT + 32 + quad * 8);
            float bias = (p == 0) ? bqn[n] * QSCL : (p == 1) ? bkn[n] : bvn[n];
            #pragma unroll
            for (int tt = 0; tt < 4; ++tt) {
                f32x4 c = __builtin_amdgcn_mfma_f32_16x16x32_bf16(a[tt][0], b0, (f32x4){0,0,0,0}, 0, 0, 0);
                c = __builtin_amdgcn_mfma_f32_16x16x32_bf16(a[tt][1], bb, c, 0, 0, 0);
                #pragma unroll
                for (int r = 0; r < 4; ++r) {
                    int tok = tok0 + tt * 16 + quad * 4 + r;
                    int bb0 = tok / S1C, ss0 = tok % S1C;
                    int bh = bb0 * NHD + w;
                    short val = f2b(c[r] + bias);
                    if (p == 0)      qb[((size_t)bh * SPAD + ss0) * 16 + lo] = val;
                    else if (p == 1) kb[((size_t)bh * SPAD + ss0) * 16 + lo] = val;
                    else             vbt[((size_t)bh * 16 + lo) * SPAD + ss0] = val;
                }
            }
        }
    }
}

// ---------------------------------------------------------------------------
// Kernel 6: head MLPs. One block (64 thr) per batch element.
// ---------------------------------------------------------------------------
__global__ __launch_bounds__(64) void k_head(
    const float* __restrict__ x, fp proj_vars, fp param_vars,
    const int* __restrict__ materials,
    fp pw1, fp pb1, fp pw2, fp pb2, fp pw3, fp pb3,
    fp pw4, fp pb4, fp pw5, fp pb5,
    fp ipw1, fp ipb1, fp ipw2, fp ipb2,
    fp hw1, fp hb1, fp hw2, fp hb2, fp hw3, fp hb3,
    float* __restrict__ out)
{
    int b = blockIdx.x;
    int tid = threadIdx.x;
    __shared__ float A[80], Bf[80], pp[8], mi[32];

    if (tid < 3) A[tid] = proj_vars[b * 3 + tid];
    A[3 + tid] = x[((size_t)b * S1C + 0) * DD + tid];
    __syncthreads();

    if (tid < 34) {
        float a = pb1[tid];
        for (int i = 0; i < 67; ++i) a += A[i] * pw1[i * 34 + tid];
        Bf[tid] = gelu_exact(a);
    }
    __syncthreads();
    if (tid < 11) {
        float a = pb2[tid];
        for (int i = 0; i < 34; ++i) a += Bf[i] * pw2[i * 11 + tid];
        A[tid] = gelu_exact(a);
    }
    __syncthreads();
    if (tid < 36) {
        float a = pb3[tid];
        for (int i = 0; i < 11; ++i) a += A[i] * pw3[i * 36 + tid];
        Bf[tid] = gelu_exact(a);
    }
    __syncthreads();
    if (tid < 22) {
        float a = pb4[tid];
        for (int i = 0; i < 36; ++i) a += Bf[i] * pw4[i * 22 + tid];
        A[tid] = gelu_exact(a);
    }
    __syncthreads();
    if (tid < 24) {
        float a = pb5[tid];
        for (int i = 0; i < 22; ++i) a += A[i] * pw5[i * 24 + tid];
        mi[3 + tid] = a;
    }
    if (tid < 3) {
        float a = ipb1[tid];
        for (int i = 0; i < 3; ++i) a += param_vars[b * 3 + i] * ipw1[i * 3 + tid];
        pp[tid] = gelu_exact(a);
    }
    __syncthreads();
    if (tid < 3) {
        float a = ipb2[tid];
        for (int i = 0; i < 3; ++i) a += pp[i] * ipw2[i * 3 + tid];
        mi[tid] = a;
    }
    __syncthreads();

    int m = materials[b];
    if (tid < 15) {
        float a = hb1[m * 15 + tid];
        for (int i = 0; i < 27; ++i) a += mi[i] * hw1[(m * 27 + i) * 15 + tid];
        A[tid] = gelu_exact(a);
    }
    __syncthreads();
    if (tid < 18) {
        float a = hb2[m * 18 + tid];
        for (int i = 0; i < 15; ++i) a += A[i] * hw2[(m * 15 + i) * 18 + tid];
        Bf[tid] = gelu_exact(a);
    }
    __syncthreads();
    if (tid == 0) {
        float a = hb3[m];
        for (int i = 0; i < 18; ++i) a += Bf[i] * hw3[m * 18 + i];
        out[b] = a;
    }
}

// ---------------------------------------------------------------------------
extern "C" void kernel_launch(void* const* d_in, const int* in_sizes, int n_in,
                              void* d_out, int out_size, void* d_ws, size_t ws_size,
                              hipStream_t stream) {
    fp in_seq     = (fp)d_in[0];
    fp proj_vars  = (fp)d_in[1];
    fp param_vars = (fp)d_in[2];
    const int* materials = (const int*)d_in[3];
    fp enc_w1 = (fp)d_in[4];
    fp enc_b1 = (fp)d_in[5];
    fp enc_w2 = (fp)d_in[6];
    fp enc_b2 = (fp)d_in[7];
    fp sos    = (fp)d_in[8];
    fp tl_wq  = (fp)d_in[9];
    fp tl_wk  = (fp)d_in[10];
    fp tl_wv  = (fp)d_in[11];
    fp tl_bq  = (fp)d_in[12];
    fp tl_bk  = (fp)d_in[13];
    fp tl_bv  = (fp)d_in[14];
    fp tl_wo  = (fp)d_in[15];
    fp tl_bo  = (fp)d_in[16];
    fp tl_ln1s = (fp)d_in[17];
    fp tl_ln1b = (fp)d_in[18];
    fp tl_ln2s = (fp)d_in[19];
    fp tl_ln2b = (fp)d_in[20];
    fp tl_fw1 = (fp)d_in[21];
    fp tl_fb1 = (fp)d_in[22];
    fp tl_fw2 = (fp)d_in[23];
    fp tl_fb2 = (fp)d_in[24];
    fp pw1 = (fp)d_in[25]; fp pb1 = (fp)d_in[26];
    fp pw2 = (fp)d_in[27]; fp pb2 = (fp)d_in[28];
    fp pw3 = (fp)d_in[29]; fp pb3 = (fp)d_in[30];
    fp pw4 = (fp)d_in[31]; fp pb4 = (fp)d_in[32];
    fp pw5 = (fp)d_in[33]; fp pb5 = (fp)d_in[34];
    fp ipw1 = (fp)d_in[35]; fp ipb1 = (fp)d_in[36];
    fp ipw2 = (fp)d_in[37]; fp ipb2 = (fp)d_in[38];
    fp hw1 = (fp)d_in[39]; fp hb1 = (fp)d_in[40];
    fp hw2 = (fp)d_in[41]; fp hb2 = (fp)d_in[42];
    fp hw3 = (fp)d_in[43]; fp hb3 = (fp)d_in[44];

    // Workspace layout
    float* x  = (float*)d_ws;                           // NTOK*64 fp32
    short* ob = (short*)(x + (size_t)NTOK * DD);        // NTOK*64 bf16
    short* xb = ob + (size_t)NTOK * DD;                 // NTOK*64 bf16
    short* qb = xb + (size_t)NTOK * DD;
    short* kb = qb + (size_t)NBH * SPAD * 16;
    short* vbt = kb + (size_t)NBH * SPAD * 16;
    short* wqkvT = vbt + (size_t)NBH * 16 * SPAD;       // 3 x 12288
    short* woT = wqkvT + (size_t)NLAY * 12288;          // 3 x 4096
    short* w1T = woT + (size_t)NLAY * 4096;             // 3 x 16384
    short* w2T = w1T + (size_t)NLAY * 16384;            // 3 x 16384

    k_wconv<<<dim3(192, NLAY), 256, 0, stream>>>(
        tl_wq, tl_wk, tl_wv, tl_wo, tl_fw1, tl_fw2, wqkvT, woT, w1T, w2T);
    k_zero<<<NBH, 64, 0, stream>>>(qb, kb, vbt);
    k_encode<<<NTOK / 4, 256, 0, stream>>>(in_seq, enc_w1, enc_b1, enc_w2, enc_b2, sos, x, xb);

    k_qkv<<<NTOK / FTT, 256, 0, stream>>>(
        xb, wqkvT,
        tl_bq, tl_bk, tl_bv,
        qb, kb, vbt);

    for (int l = 0; l < NLAY; ++l) {
        k_attn<<<NBH * TGRP2, 256, 0, stream>>>(qb, kb, vbt, ob);
        int ln = (l + 1 < NLAY) ? (l + 1) : l;   // dummy ptrs for last layer
        k_block<<<NTOK / FT2, 256, 0, stream>>>(
            ob, x,
            woT + (size_t)l * 4096, tl_bo + (size_t)l * DD,
            tl_ln1s + (size_t)l * DD, tl_ln1b + (size_t)l * DD,
            w1T + (size_t)l * 16384, tl_fb1 + (size_t)l * DFFC,
            w2T + (size_t)l * 16384, tl_fb2 + (size_t)l * DD,
            tl_ln2s + (size_t)l * DD, tl_ln2b + (size_t)l * DD,
            wqkvT + (size_t)ln * 12288,
            tl_bq + (size_t)ln * DD, tl_bk + (size_t)ln * DD, tl_bv + (size_t)ln * DD,
            qb, kb, vbt,
            (l + 1 < NLAY) ? 1 : 0);
    }

    k_head<<<BB, 64, 0, stream>>>(
        x, proj_vars, param_vars, materials,
        pw1, pb1, pw2, pb2, pw3, pb3, pw4, pb4, pw5, pb5,
        ipw1, ipb1, ipw2, ipb2,
        hw1, hb1, hw2, hb2, hw3, hb3,
        (float*)d_out);
}

// Round 16
// 524.362 us; speedup vs baseline: 1.0578x; 1.0578x over previous
//
#include <hip/hip_runtime.h>
#include <hip/hip_bf16.h>
#include <math.h>

// Problem constants
#define BB   64
#define SS   1024
#define S1C  1025
#define DD   64
#define NHD  4
#define NBH  (BB * NHD)      // 256
#define DHD  16
#define DFFC 256
#define NLAY 3
#define NTOK (BB * S1C)      // 65600 = 32 * 2050
#define SPAD 1056            // padded key/seq length (66 * 16)
#define TGRP2 9              // tile-pair groups: wave covers T0=grp*4+w, T1=T0+36
#define FTQ   32             // tokens per block (k_qkv) - 2 token-tiles/wave
#define FT2   32             // tokens per block (k_block) - 2 token-tiles/wave
#define HPAD 264             // hid row stride in shorts
#define OPAD 68              // ot row stride in floats
#define YPAD 72              // ys row stride in shorts
#define QSCL 0.36067376022224085f   // 0.25 * log2(e) folded into q

typedef const float* fp;
typedef __attribute__((ext_vector_type(8))) short bf16x8;
typedef __attribute__((ext_vector_type(4))) float f32x4;

#if __has_builtin(__builtin_amdgcn_exp2f)
#define RAW_EXP2(x) __builtin_amdgcn_exp2f(x)
#else
#define RAW_EXP2(x) __expf(0.6931471805599453f * (x))
#endif
#if __has_builtin(__builtin_amdgcn_rcpf)
#define RAW_RCP(x) __builtin_amdgcn_rcpf(x)
#else
#define RAW_RCP(x) (1.0f / (x))
#endif

__device__ __forceinline__ float gelu_exact(float x) {
    return 0.5f * x * (1.0f + erff(x * 0.7071067811865475f));
}
// A&S 7.1.26 erf approximation, |err| <= 1.5e-7 (<< bf16 rounding noise)
__device__ __forceinline__ float erf_fast(float x) {
    float ax = fabsf(x);
    float t = RAW_RCP(1.0f + 0.3275911f * ax);
    float p = t * (0.254829592f + t * (-0.284496736f + t * (1.421413741f +
              t * (-1.453152027f + t * 1.061405429f))));
    float e = RAW_EXP2(ax * ax * -1.4426950408889634f);
    float r = 1.0f - p * e;
    return copysignf(r, x);
}
__device__ __forceinline__ float gelu_fast(float x) {
    return 0.5f * x * (1.0f + erf_fast(x * 0.7071067811865475f));
}
// RTNE float->bf16 (finite values), 3 ops
__device__ __forceinline__ short f2b(float f) {
    unsigned u = __float_as_uint(f);
    return (short)((u + 0x7fffu + ((u >> 16) & 1u)) >> 16);
}
// fast bf16 for positive finite values (round-nearest-up)
__device__ __forceinline__ short f2b_pos(float f) {
    return (short)((__float_as_uint(f) + 0x8000u) >> 16);
}

// ---------------------------------------------------------------------------
// Kernel W: one-shot weight convert+transpose to bf16 [n][k] fragments.
// ---------------------------------------------------------------------------
__global__ __launch_bounds__(256) void k_wconv(
    fp wq, fp wk, fp wv, fp wo, fp w1, fp w2,
    short* __restrict__ wqkvT, short* __restrict__ woT,
    short* __restrict__ w1T, short* __restrict__ w2T)
{
    int l = blockIdx.y;
    int i = blockIdx.x * 256 + threadIdx.x;
    if (i < 12288) {
        int p = i >> 12, rem = i & 4095;
        int d = rem >> 6, j = rem & 63;
        fp src = (p == 0 ? wq : p == 1 ? wk : wv) + (size_t)l * 4096;
        float v = src[j * 64 + d];
        if (p == 0) v *= QSCL;
        wqkvT[(size_t)l * 12288 + i] = f2b(v);
    } else if (i < 16384) {
        int rem = i - 12288;
        woT[(size_t)l * 4096 + rem] = f2b(wo[(size_t)l * 4096 + (rem & 63) * 64 + (rem >> 6)]);
    } else if (i < 32768) {
        int rem = i - 16384;
        w1T[(size_t)l * 16384 + rem] = f2b(w1[(size_t)l * 16384 + (rem & 63) * 256 + (rem >> 6)]);
    } else {
        int rem = i - 32768;
        w2T[(size_t)l * 16384 + rem] = f2b(w2[(size_t)l * 16384 + (rem & 255) * 64 + (rem >> 8)]);
    }
}

// ---------------------------------------------------------------------------
// Kernel 0: zero the pad regions of the bf16 q/k/v buffers (rows 1025..1055).
// ---------------------------------------------------------------------------
__global__ __launch_bounds__(64) void k_zero(
    short* __restrict__ qb, short* __restrict__ kb, short* __restrict__ vbt)
{
    int bh = blockIdx.x, t = threadIdx.x;
    for (int i = t; i < 31 * 16; i += 64) {
        int r = i >> 4, c = i & 15;
        size_t idx = ((size_t)bh * SPAD + 1025 + r) * 16 + c;
        qb[idx] = 0; kb[idx] = 0;
    }
    for (int i = t; i < 16 * 31; i += 64) {
        int e = i / 31, c = i % 31;
        vbt[((size_t)bh * 16 + e) * SPAD + 1025 + c] = 0;
    }
}

// ---------------------------------------------------------------------------
// Kernel 1: encoder MLP + sos concat + positional encoding -> x fp32, xb bf16
// ---------------------------------------------------------------------------
__global__ __launch_bounds__(256) void k_encode(
    fp in_seq, fp enc_w1, fp enc_b1, fp enc_w2, fp enc_b2, fp sos,
    float* __restrict__ x, short* __restrict__ xb)
{
    int t = threadIdx.x;
    int w = t >> 6, d = t & 63;
    int tok = blockIdx.x * 4 + w;
    int b = tok / S1C, s = tok % S1C;
    __shared__ float e[4][48];
    float val;
    if (s == 0) {
        val = sos[d];
    } else {
        float tin = in_seq[b * SS + (s - 1)];
        if (d < 48) e[w][d] = gelu_fast(tin * enc_w1[d] + enc_b1[d]);
        float acc = enc_b2[d];
        for (int j = 0; j < 48; ++j) acc += e[w][j] * enc_w2[j * DD + d];
        val = acc;
    }
    int i2 = (d >> 1) * 2;
    float factor = RAW_EXP2((float)i2 * (-9.210340371976184f / 64.0f) * 1.4426950408889634f);
    float ang = (float)s * factor;
    val += (d & 1) ? __cosf(ang) : __sinf(ang);
    x[(size_t)tok * DD + d] = val;
    xb[(size_t)tok * DD + d] = f2b(val);
}

// ---------------------------------------------------------------------------
// Kernel 2: MFMA Q/K/V projection for layer 0. 32 tokens/block, 2 token-tiles
// per wave: each weight fragment feeds 2 MFMAs.
// ---------------------------------------------------------------------------
__global__ __launch_bounds__(256) void k_qkv(
    const short* __restrict__ xb, const short* __restrict__ wqkvT,
    fp bq, fp bk, fp bv,
    short* __restrict__ qb, short* __restrict__ kb, short* __restrict__ vbt)
{
    int blk = blockIdx.x, t = threadIdx.x;
    int tok0 = blk * FTQ;
    int w = t >> 6, l = t & 63;
    int quad = l >> 4, lo = l & 15;

    const short* xp0 = xb + ((size_t)(tok0 + lo)) * DD;
    const short* xp1 = xb + ((size_t)(tok0 + 16 + lo)) * DD;
    bf16x8 a0 = *(const bf16x8*)(xp0 + quad * 8);
    bf16x8 a1 = *(const bf16x8*)(xp0 + 32 + quad * 8);
    bf16x8 a2 = *(const bf16x8*)(xp1 + quad * 8);
    bf16x8 a3 = *(const bf16x8*)(xp1 + 32 + quad * 8);

    int n = w * 16 + lo;
    #pragma unroll
    for (int p = 0; p < 3; ++p) {
        const short* wT = wqkvT + (size_t)p * 4096 + (size_t)n * 64;
        bf16x8 b0 = *(const bf16x8*)(wT + quad * 8);
        bf16x8 b1 = *(const bf16x8*)(wT + 32 + quad * 8);
        f32x4 c0 = __builtin_amdgcn_mfma_f32_16x16x32_bf16(a0, b0, (f32x4){0,0,0,0}, 0, 0, 0);
        c0 = __builtin_amdgcn_mfma_f32_16x16x32_bf16(a1, b1, c0, 0, 0, 0);
        f32x4 c1 = __builtin_amdgcn_mfma_f32_16x16x32_bf16(a2, b0, (f32x4){0,0,0,0}, 0, 0, 0);
        c1 = __builtin_amdgcn_mfma_f32_16x16x32_bf16(a3, b1, c1, 0, 0, 0);
        float bias = (p == 0) ? bq[n] * QSCL : (p == 1) ? bk[n] : bv[n];
        #pragma unroll
        for (int r = 0; r < 4; ++r) {
            int tok = tok0 + quad * 4 + r;
            int bb0 = tok / S1C, ss0 = tok % S1C;
            int bh = bb0 * NHD + w;
            short val = f2b(c0[r] + bias);
            int tok2 = tok + 16;
            int bb1 = tok2 / S1C, ss1 = tok2 % S1C;
            int bh2 = bb1 * NHD + w;
            short val2 = f2b(c1[r] + bias);
            if (p == 0) {
                qb[((size_t)bh * SPAD + ss0) * 16 + lo] = val;
                qb[((size_t)bh2 * SPAD + ss1) * 16 + lo] = val2;
            } else if (p == 1) {
                kb[((size_t)bh * SPAD + ss0) * 16 + lo] = val;
                kb[((size_t)bh2 * SPAD + ss1) * 16 + lo] = val2;
            } else {
                vbt[((size_t)bh * 16 + lo) * SPAD + ss0] = val;
                vbt[((size_t)bh2 * 16 + lo) * SPAD + ss1] = val2;
            }
        }
    }
}

// ---------------------------------------------------------------------------
// Kernel 3: single-pass flash MFMA attention, two q-tiles per wave
// (r13 best-measured version).
// ---------------------------------------------------------------------------
__global__ __launch_bounds__(256) void k_attn(
    const short* __restrict__ qb, const short* __restrict__ kb,
    const short* __restrict__ vbt, short* __restrict__ ob)
{
    int bid = blockIdx.x;
    int bh  = bid % NBH;           // 9 blocks of a bh share bid%8 (XCD/L2)
    int grp = bid / NBH;           // 0..8
    int b = bh >> 2, h = bh & 3;
    int t = threadIdx.x;
    int w = t >> 6, l = t & 63;
    int quad = l >> 4, lo = l & 15;
    int t0 = grp * 4 + w;          // 0..35
    int t1 = t0 + 36;              // 36..71
    if (t1 > 65) t1 = 65;          // clamp into zero-pad
    int qg0 = t0 * 16, qg1 = t1 * 16;

    __shared__ short pt_all[4][2][16][40];
    short (*pt0)[40] = pt_all[w][0];
    short (*pt1)[40] = pt_all[w][1];

    const short* qbase = qb + (size_t)bh * SPAD * 16;
    const short* kbase = kb + (size_t)bh * SPAD * 16;
    const short* vbase = vbt + (size_t)bh * 16 * SPAD;

    bf16x8 aQ0 = {0,0,0,0,0,0,0,0}, aQ1 = {0,0,0,0,0,0,0,0};
    if (quad < 2) {
        aQ0 = *(const bf16x8*)(qbase + ((size_t)(qg0 + lo)) * 16 + quad * 8);
        aQ1 = *(const bf16x8*)(qbase + ((size_t)(qg1 + lo)) * 16 + quad * 8);
    }

    const short ONE = 0x3F80;
    bf16x8 aOne = {ONE, ONE, ONE, ONE, ONE, ONE, ONE, ONE};

    f32x4 oc0 = {0.f,0.f,0.f,0.f}, oc1 = {0.f,0.f,0.f,0.f};
    f32x4 dn0 = {0.f,0.f,0.f,0.f}, dn1 = {0.f,0.f,0.f,0.f};

    for (int ch = 0; ch < 32; ++ch) {
        #pragma unroll
        for (int t01 = 0; t01 < 2; ++t01) {
            int krow = ch * 32 + t01 * 16 + lo;
            bf16x8 bK = *(const bf16x8*)(kbase + (size_t)krow * 16 + (quad & 1) * 8);
            f32x4 c0 = __builtin_amdgcn_mfma_f32_16x16x32_bf16(
                aQ0, bK, (f32x4){0.f,0.f,0.f,0.f}, 0, 0, 0);
            f32x4 c1 = __builtin_amdgcn_mfma_f32_16x16x32_bf16(
                aQ1, bK, (f32x4){0.f,0.f,0.f,0.f}, 0, 0, 0);
            #pragma unroll
            for (int r = 0; r < 4; ++r) {
                pt0[quad * 4 + r][t01 * 16 + lo] = f2b_pos(RAW_EXP2(c0[r]));
                pt1[quad * 4 + r][t01 * 16 + lo] = f2b_pos(RAW_EXP2(c1[r]));
            }
        }
        bf16x8 aV = *(const bf16x8*)(vbase + (size_t)lo * SPAD + ch * 32 + quad * 8);
        bf16x8 pB0 = *(const bf16x8*)&pt0[lo][quad * 8];
        oc0 = __builtin_amdgcn_mfma_f32_16x16x32_bf16(aV, pB0, oc0, 0, 0, 0);
        dn0 = __builtin_amdgcn_mfma_f32_16x16x32_bf16(aOne, pB0, dn0, 0, 0, 0);
        bf16x8 pB1 = *(const bf16x8*)&pt1[lo][quad * 8];
        oc1 = __builtin_amdgcn_mfma_f32_16x16x32_bf16(aV, pB1, oc1, 0, 0, 0);
        dn1 = __builtin_amdgcn_mfma_f32_16x16x32_bf16(aOne, pB1, dn1, 0, 0, 0);
    }
    {   // tail chunk: keys 1024..1055, only key 1024 valid
        #pragma unroll
        for (int t01 = 0; t01 < 2; ++t01) {
            int krow = 1024 + t01 * 16 + lo;
            bf16x8 bK = *(const bf16x8*)(kbase + (size_t)krow * 16 + (quad & 1) * 8);
            f32x4 c0 = __builtin_amdgcn_mfma_f32_16x16x32_bf16(
                aQ0, bK, (f32x4){0.f,0.f,0.f,0.f}, 0, 0, 0);
            f32x4 c1 = __builtin_amdgcn_mfma_f32_16x16x32_bf16(
                aQ1, bK, (f32x4){0.f,0.f,0.f,0.f}, 0, 0, 0);
            bool valid = (krow <= 1024);
            #pragma unroll
            for (int r = 0; r < 4; ++r) {
                pt0[quad * 4 + r][t01 * 16 + lo] = f2b_pos(valid ? RAW_EXP2(c0[r]) : 0.f);
                pt1[quad * 4 + r][t01 * 16 + lo] = f2b_pos(valid ? RAW_EXP2(c1[r]) : 0.f);
            }
        }
        bf16x8 aV = *(const bf16x8*)(vbase + (size_t)lo * SPAD + 1024 + quad * 8);
        bf16x8 pB0 = *(const bf16x8*)&pt0[lo][quad * 8];
        oc0 = __builtin_amdgcn_mfma_f32_16x16x32_bf16(aV, pB0, oc0, 0, 0, 0);
        dn0 = __builtin_amdgcn_mfma_f32_16x16x32_bf16(aOne, pB0, dn0, 0, 0, 0);
        bf16x8 pB1 = *(const bf16x8*)&pt1[lo][quad * 8];
        oc1 = __builtin_amdgcn_mfma_f32_16x16x32_bf16(aV, pB1, oc1, 0, 0, 0);
        dn1 = __builtin_amdgcn_mfma_f32_16x16x32_bf16(aOne, pB1, dn1, 0, 0, 0);
    }

    {
        int qrow = qg0 + lo;
        if (qrow < S1C) {
            float inv = 1.0f / dn0[0];
            unsigned p0 = (unsigned short)f2b(oc0[0] * inv) | ((unsigned)(unsigned short)f2b(oc0[1] * inv) << 16);
            unsigned p1 = (unsigned short)f2b(oc0[2] * inv) | ((unsigned)(unsigned short)f2b(oc0[3] * inv) << 16);
            *(uint2*)(ob + ((size_t)b * S1C + qrow) * DD + h * DHD + quad * 4) = make_uint2(p0, p1);
        }
    }
    {
        int qrow = qg1 + lo;
        if (qrow < S1C) {
            float inv = 1.0f / dn1[0];
            unsigned p0 = (unsigned short)f2b(oc1[0] * inv) | ((unsigned)(unsigned short)f2b(oc1[1] * inv) << 16);
            unsigned p1 = (unsigned short)f2b(oc1[2] * inv) | ((unsigned)(unsigned short)f2b(oc1[3] * inv) << 16);
            *(uint2*)(ob + ((size_t)b * S1C + qrow) * DD + h * DHD + quad * 4) = make_uint2(p0, p1);
        }
    }
}

// ---------------------------------------------------------------------------
// Kernel 4: fused transformer tail: oproj(MFMA) + LN1 + FFN(MFMA) + LN2
// + next-layer QKV(MFMA). 32 tokens/block (2 token-tiles per wave) —
// r13 best-measured version.
// ---------------------------------------------------------------------------
__global__ __launch_bounds__(256) void k_block(
    const short* __restrict__ ob, float* __restrict__ x,
    const short* __restrict__ woT, fp bo, fp ln1s, fp ln1b,
    const short* __restrict__ w1T, fp b1, const short* __restrict__ w2T, fp b2,
    fp ln2s, fp ln2b,
    const short* __restrict__ wqkvTn, fp bqn, fp bkn, fp bvn,
    short* __restrict__ qb, short* __restrict__ kb, short* __restrict__ vbt,
    int has_next)
{
    int blk = blockIdx.x, t = threadIdx.x;
    int tok0 = blk * FT2;
    int w = t >> 6, l = t & 63;
    int quad = l >> 4, lo = l & 15;

    __shared__ float otf[FT2][OPAD];
    __shared__ short ys[FT2][YPAD];
    __shared__ short hid[FT2][HPAD];

    // ---- oproj (both token-tiles, weights loaded once) ----
    {
        const short* obp0 = ob + ((size_t)(tok0 + lo)) * DD;
        const short* obp1 = ob + ((size_t)(tok0 + 16 + lo)) * DD;
        bf16x8 a0 = *(const bf16x8*)(obp0 + quad * 8);
        bf16x8 a1 = *(const bf16x8*)(obp0 + 32 + quad * 8);
        bf16x8 a2 = *(const bf16x8*)(obp1 + quad * 8);
        bf16x8 a3 = *(const bf16x8*)(obp1 + 32 + quad * 8);
        int n = w * 16 + lo;
        const short* wT = woT + (size_t)n * 64;
        bf16x8 b0 = *(const bf16x8*)(wT + quad * 8);
        bf16x8 bb = *(const bf16x8*)(wT + 32 + quad * 8);
        f32x4 c0 = __builtin_amdgcn_mfma_f32_16x16x32_bf16(a0, b0, (f32x4){0,0,0,0}, 0, 0, 0);
        c0 = __builtin_amdgcn_mfma_f32_16x16x32_bf16(a1, bb, c0, 0, 0, 0);
        f32x4 c1 = __builtin_amdgcn_mfma_f32_16x16x32_bf16(a2, b0, (f32x4){0,0,0,0}, 0, 0, 0);
        c1 = __builtin_amdgcn_mfma_f32_16x16x32_bf16(a3, bb, c1, 0, 0, 0);
        float bov = bo[n];
        #pragma unroll
        for (int r = 0; r < 4; ++r) {
            otf[quad * 4 + r][n] = c0[r] + bov;
            otf[16 + quad * 4 + r][n] = c1[r] + bov;
        }
    }
    __syncthreads();

    // ---- LN1: wave w -> tokens w*8..w*8+7, lane = dim d ----
    int d = l;
    float yv[8];
    {
        float s1 = ln1s[d], bl1 = ln1b[d];
        #pragma unroll
        for (int i = 0; i < 8; ++i) {
            int tt = w * 8 + i;
            float val = otf[tt][d] + x[(size_t)(tok0 + tt) * DD + d];
            float sum = val, vs = val * val;
            #pragma unroll
            for (int off = 32; off > 0; off >>= 1) {
                sum += __shfl_xor(sum, off, 64);
                vs  += __shfl_xor(vs, off, 64);
            }
            float mean = sum * (1.0f / 64.0f);
            float var = vs * (1.0f / 64.0f) - mean * mean;
            float y = (val - mean) * rsqrtf(var + 1e-5f) * s1 + bl1;
            yv[i] = y;
            ys[tt][d] = f2b(y);
        }
    }
    __syncthreads();

    // ---- FFN phase 1: hid = gelu(y @ w1 + b1), both tiles ----
    {
        bf16x8 a0 = *(const bf16x8*)&ys[lo][quad * 8];
        bf16x8 a1 = *(const bf16x8*)&ys[lo][32 + quad * 8];
        bf16x8 a2 = *(const bf16x8*)&ys[16 + lo][quad * 8];
        bf16x8 a3 = *(const bf16x8*)&ys[16 + lo][32 + quad * 8];
        #pragma unroll
        for (int i = 0; i < 4; ++i) {
            int n = w * 64 + i * 16 + lo;
            const short* wT = w1T + (size_t)n * 64;
            bf16x8 b0 = *(const bf16x8*)(wT + quad * 8);
            bf16x8 bb = *(const bf16x8*)(wT + 32 + quad * 8);
            f32x4 c0 = __builtin_amdgcn_mfma_f32_16x16x32_bf16(a0, b0, (f32x4){0,0,0,0}, 0, 0, 0);
            c0 = __builtin_amdgcn_mfma_f32_16x16x32_bf16(a1, bb, c0, 0, 0, 0);
            f32x4 c1 = __builtin_amdgcn_mfma_f32_16x16x32_bf16(a2, b0, (f32x4){0,0,0,0}, 0, 0, 0);
            c1 = __builtin_amdgcn_mfma_f32_16x16x32_bf16(a3, bb, c1, 0, 0, 0);
            float b1v = b1[n];
            #pragma unroll
            for (int r = 0; r < 4; ++r) {
                hid[quad * 4 + r][n] = f2b(gelu_fast(c0[r] + b1v));
                hid[16 + quad * 4 + r][n] = f2b(gelu_fast(c1[r] + b1v));
            }
        }
    }
    __syncthreads();

    // ---- FFN phase 2: out = hid @ w2 + b2 (K=256), both tiles ----
    {
        f32x4 c20 = {0.f,0.f,0.f,0.f}, c21 = {0.f,0.f,0.f,0.f};
        const short* wT2 = w2T + (size_t)(w * 16 + lo) * 256;
        #pragma unroll
        for (int kc = 0; kc < 8; ++kc) {
            bf16x8 b2f = *(const bf16x8*)(wT2 + kc * 32 + quad * 8);
            bf16x8 a20 = *(const bf16x8*)&hid[lo][kc * 32 + quad * 8];
            bf16x8 a21 = *(const bf16x8*)&hid[16 + lo][kc * 32 + quad * 8];
            c20 = __builtin_amdgcn_mfma_f32_16x16x32_bf16(a20, b2f, c20, 0, 0, 0);
            c21 = __builtin_amdgcn_mfma_f32_16x16x32_bf16(a21, b2f, c21, 0, 0, 0);
        }
        float b2v = b2[w * 16 + lo];
        #pragma unroll
        for (int r = 0; r < 4; ++r) {
            otf[quad * 4 + r][w * 16 + lo] = c20[r] + b2v;
            otf[16 + quad * 4 + r][w * 16 + lo] = c21[r] + b2v;
        }
    }
    __syncthreads();

    // ---- LN2: residual = yv (registers) ----
    {
        float s2 = ln2s[d], bl2 = ln2b[d];
        #pragma unroll
        for (int i = 0; i < 8; ++i) {
            int tt = w * 8 + i;
            float val = otf[tt][d] + yv[i];
            float sum = val, vs = val * val;
            #pragma unroll
            for (int off = 32; off > 0; off >>= 1) {
                sum += __shfl_xor(sum, off, 64);
                vs  += __shfl_xor(vs, off, 64);
            }
            float mean = sum * (1.0f / 64.0f);
            float var = vs * (1.0f / 64.0f) - mean * mean;
            float y = (val - mean) * rsqrtf(var + 1e-5f) * s2 + bl2;
            x[(size_t)(tok0 + tt) * DD + d] = y;
            ys[tt][d] = f2b(y);
        }
    }
    __syncthreads();

    // ---- next-layer QKV, both tiles ----
    if (has_next) {
        bf16x8 a0 = *(const bf16x8*)&ys[lo][quad * 8];
        bf16x8 a1 = *(const bf16x8*)&ys[lo][32 + quad * 8];
        bf16x8 a2 = *(const bf16x8*)&ys[16 + lo][quad * 8];
        bf16x8 a3 = *(const bf16x8*)&ys[16 + lo][32 + quad * 8];
        int n = w * 16 + lo;
        #pragma unroll
        for (int p = 0; p < 3; ++p) {
            const short* wT = wqkvTn + (size_t)p * 4096 + (size_t)n * 64;
            bf16x8 b0 = *(const bf16x8*)(wT + quad * 8);
            bf16x8 bb = *(const bf16x8*)(wT + 32 + quad * 8);
            f32x4 c0 = __builtin_amdgcn_mfma_f32_16x16x32_bf16(a0, b0, (f32x4){0,0,0,0}, 0, 0, 0);
            c0 = __builtin_amdgcn_mfma_f32_16x16x32_bf16(a1, bb, c0, 0, 0, 0);
            f32x4 c1 = __builtin_amdgcn_mfma_f32_16x16x32_bf16(a2, b0, (f32x4){0,0,0,0}, 0, 0, 0);
            c1 = __builtin_amdgcn_mfma_f32_16x16x32_bf16(a3, bb, c1, 0, 0, 0);
            float bias = (p == 0) ? bqn[n] * QSCL : (p == 1) ? bkn[n] : bvn[n];
            #pragma unroll
            for (int r = 0; r < 4; ++r) {
                int tok = tok0 + quad * 4 + r;
                int bb0 = tok / S1C, ss0 = tok % S1C;
                int bh = bb0 * NHD + w;
                short val = f2b(c0[r] + bias);
                int tok2 = tok + 16;
                int bb1 = tok2 / S1C, ss1 = tok2 % S1C;
                int bh2 = bb1 * NHD + w;
                short val2 = f2b(c1[r] + bias);
                if (p == 0) {
                    qb[((size_t)bh * SPAD + ss0) * 16 + lo] = val;
                    qb[((size_t)bh2 * SPAD + ss1) * 16 + lo] = val2;
                } else if (p == 1) {
                    kb[((size_t)bh * SPAD + ss0) * 16 + lo] = val;
                    kb[((size_t)bh2 * SPAD + ss1) * 16 + lo] = val2;
                } else {
                    vbt[((size_t)bh * 16 + lo) * SPAD + ss0] = val;
                    vbt[((size_t)bh2 * 16 + lo) * SPAD + ss1] = val2;
                }
            }
        }
    }
}

// ---------------------------------------------------------------------------
// Kernel 6: head MLPs. One block (64 thr) per batch element.
// ---------------------------------------------------------------------------
__global__ __launch_bounds__(64) void k_head(
    const float* __restrict__ x, fp proj_vars, fp param_vars,
    const int* __restrict__ materials,
    fp pw1, fp pb1, fp pw2, fp pb2, fp pw3, fp pb3,
    fp pw4, fp pb4, fp pw5, fp pb5,
    fp ipw1, fp ipb1, fp ipw2, fp ipb2,
    fp hw1, fp hb1, fp hw2, fp hb2, fp hw3, fp hb3,
    float* __restrict__ out)
{
    int b = blockIdx.x;
    int tid = threadIdx.x;
    __shared__ float A[80], Bf[80], pp[8], mi[32];

    if (tid < 3) A[tid] = proj_vars[b * 3 + tid];
    A[3 + tid] = x[((size_t)b * S1C + 0) * DD + tid];
    __syncthreads();

    if (tid < 34) {
        float a = pb1[tid];
        for (int i = 0; i < 67; ++i) a += A[i] * pw1[i * 34 + tid];
        Bf[tid] = gelu_exact(a);
    }
    __syncthreads();
    if (tid < 11) {
        float a = pb2[tid];
        for (int i = 0; i < 34; ++i) a += Bf[i] * pw2[i * 11 + tid];
        A[tid] = gelu_exact(a);
    }
    __syncthreads();
    if (tid < 36) {
        float a = pb3[tid];
        for (int i = 0; i < 11; ++i) a += A[i] * pw3[i * 36 + tid];
        Bf[tid] = gelu_exact(a);
    }
    __syncthreads();
    if (tid < 22) {
        float a = pb4[tid];
        for (int i = 0; i < 36; ++i) a += Bf[i] * pw4[i * 22 + tid];
        A[tid] = gelu_exact(a);
    }
    __syncthreads();
    if (tid < 24) {
        float a = pb5[tid];
        for (int i = 0; i < 22; ++i) a += A[i] * pw5[i * 24 + tid];
        mi[3 + tid] = a;
    }
    if (tid < 3) {
        float a = ipb1[tid];
        for (int i = 0; i < 3; ++i) a += param_vars[b * 3 + i] * ipw1[i * 3 + tid];
        pp[tid] = gelu_exact(a);
    }
    __syncthreads();
    if (tid < 3) {
        float a = ipb2[tid];
        for (int i = 0; i < 3; ++i) a += pp[i] * ipw2[i * 3 + tid];
        mi[tid] = a;
    }
    __syncthreads();

    int m = materials[b];
    if (tid < 15) {
        float a = hb1[m * 15 + tid];
        for (int i = 0; i < 27; ++i) a += mi[i] * hw1[(m * 27 + i) * 15 + tid];
        A[tid] = gelu_exact(a);
    }
    __syncthreads();
    if (tid < 18) {
        float a = hb2[m * 18 + tid];
        for (int i = 0; i < 15; ++i) a += A[i] * hw2[(m * 15 + i) * 18 + tid];
        Bf[tid] = gelu_exact(a);
    }
    __syncthreads();
    if (tid == 0) {
        float a = hb3[m];
        for (int i = 0; i < 18; ++i) a += Bf[i] * hw3[m * 18 + i];
        out[b] = a;
    }
}

// ---------------------------------------------------------------------------
extern "C" void kernel_launch(void* const* d_in, const int* in_sizes, int n_in,
                              void* d_out, int out_size, void* d_ws, size_t ws_size,
                              hipStream_t stream) {
    fp in_seq     = (fp)d_in[0];
    fp proj_vars  = (fp)d_in[1];
    fp param_vars = (fp)d_in[2];
    const int* materials = (const int*)d_in[3];
    fp enc_w1 = (fp)d_in[4];
    fp enc_b1 = (fp)d_in[5];
    fp enc_w2 = (fp)d_in[6];
    fp enc_b2 = (fp)d_in[7];
    fp sos    = (fp)d_in[8];
    fp tl_wq  = (fp)d_in[9];
    fp tl_wk  = (fp)d_in[10];
    fp tl_wv  = (fp)d_in[11];
    fp tl_bq  = (fp)d_in[12];
    fp tl_bk  = (fp)d_in[13];
    fp tl_bv  = (fp)d_in[14];
    fp tl_wo  = (fp)d_in[15];
    fp tl_bo  = (fp)d_in[16];
    fp tl_ln1s = (fp)d_in[17];
    fp tl_ln1b = (fp)d_in[18];
    fp tl_ln2s = (fp)d_in[19];
    fp tl_ln2b = (fp)d_in[20];
    fp tl_fw1 = (fp)d_in[21];
    fp tl_fb1 = (fp)d_in[22];
    fp tl_fw2 = (fp)d_in[23];
    fp tl_fb2 = (fp)d_in[24];
    fp pw1 = (fp)d_in[25]; fp pb1 = (fp)d_in[26];
    fp pw2 = (fp)d_in[27]; fp pb2 = (fp)d_in[28];
    fp pw3 = (fp)d_in[29]; fp pb3 = (fp)d_in[30];
    fp pw4 = (fp)d_in[31]; fp pb4 = (fp)d_in[32];
    fp pw5 = (fp)d_in[33]; fp pb5 = (fp)d_in[34];
    fp ipw1 = (fp)d_in[35]; fp ipb1 = (fp)d_in[36];
    fp ipw2 = (fp)d_in[37]; fp ipb2 = (fp)d_in[38];
    fp hw1 = (fp)d_in[39]; fp hb1 = (fp)d_in[40];
    fp hw2 = (fp)d_in[41]; fp hb2 = (fp)d_in[42];
    fp hw3 = (fp)d_in[43]; fp hb3 = (fp)d_in[44];

    // Workspace layout
    float* x  = (float*)d_ws;                           // NTOK*64 fp32
    short* ob = (short*)(x + (size_t)NTOK * DD);        // NTOK*64 bf16
    short* xb = ob + (size_t)NTOK * DD;                 // NTOK*64 bf16
    short* qb = xb + (size_t)NTOK * DD;
    short* kb = qb + (size_t)NBH * SPAD * 16;
    short* vbt = kb + (size_t)NBH * SPAD * 16;
    short* wqkvT = vbt + (size_t)NBH * 16 * SPAD;       // 3 x 12288
    short* woT = wqkvT + (size_t)NLAY * 12288;          // 3 x 4096
    short* w1T = woT + (size_t)NLAY * 4096;             // 3 x 16384
    short* w2T = w1T + (size_t)NLAY * 16384;            // 3 x 16384

    k_wconv<<<dim3(192, NLAY), 256, 0, stream>>>(
        tl_wq, tl_wk, tl_wv, tl_wo, tl_fw1, tl_fw2, wqkvT, woT, w1T, w2T);
    k_zero<<<NBH, 64, 0, stream>>>(qb, kb, vbt);
    k_encode<<<NTOK / 4, 256, 0, stream>>>(in_seq, enc_w1, enc_b1, enc_w2, enc_b2, sos, x, xb);

    k_qkv<<<NTOK / FTQ, 256, 0, stream>>>(
        xb, wqkvT,
        tl_bq, tl_bk, tl_bv,
        qb, kb, vbt);

    for (int l = 0; l < NLAY; ++l) {
        k_attn<<<NBH * TGRP2, 256, 0, stream>>>(qb, kb, vbt, ob);
        int ln = (l + 1 < NLAY) ? (l + 1) : l;   // dummy ptrs for last layer
        k_block<<<NTOK / FT2, 256, 0, stream>>>(
            ob, x,
            woT + (size_t)l * 4096, tl_bo + (size_t)l * DD,
            tl_ln1s + (size_t)l * DD, tl_ln1b + (size_t)l * DD,
            w1T + (size_t)l * 16384, tl_fb1 + (size_t)l * DFFC,
            w2T + (size_t)l * 16384, tl_fb2 + (size_t)l * DD,
            tl_ln2s + (size_t)l * DD, tl_ln2b + (size_t)l * DD,
            wqkvT + (size_t)ln * 12288,
            tl_bq + (size_t)ln * DD, tl_bk + (size_t)ln * DD, tl_bv + (size_t)ln * DD,
            qb, kb, vbt,
            (l + 1 < NLAY) ? 1 : 0);
    }

    k_head<<<BB, 64, 0, stream>>>(
        x, proj_vars, param_vars, materials,
        pw1, pb1, pw2, pb2, pw3, pb3, pw4, pb4, pw5, pb5,
        ipw1, ipb1, ipw2, ipb2,
        hw1, hb1, hw2, hb2, hw3, hb3,
        (float*)d_out);
}